// Round 13
// baseline (112.764 us; speedup 1.0000x reference)
//
#include <hip/hip_runtime.h>

#define NB   2
#define SKV  1024
#define NSQ  512
#define HIN  256
#define HA   128

// projections pre-scaled by 2*log2(e):  exp2(KSC*x) = e^{2x}
// tanh(x) = 1 - 2/(e^{2x}+1); softmax is shift-invariant so the constant
// W0+bv terms of the score are dropped entirely.
#define KSC   2.8853900817779268f   // 2*log2(e)

__device__ __forceinline__ float rlf(float v, int l) {
    return __int_as_float(__builtin_amdgcn_readlane(__float_as_int(v), l));
}

// ---------------- Kernel A: projections -> exponentials ----------------
// (R2/R6 version, unchanged — part of the best measured build.)
__global__ __launch_bounds__(512) void proj_kernel(
    const float* __restrict__ kv,
    const float* __restrict__ qy,
    const float* __restrict__ Wkv,
    const float* __restrict__ bkv,
    const float* __restrict__ Wq,
    const float* __restrict__ bq,
    float* __restrict__ ekT,
    float* __restrict__ eq)
{
    __shared__ __align__(16) float rowf[8][HIN];
    const int t  = threadIdx.x;
    const int a  = t & 127;            // output channel
    const int rh = t >> 7;             // row-pair id (0..3)
    const int r0 = blockIdx.x * 8;     // 8 rows per block
    const bool is_q = (r0 >= NB * SKV);
    const float* __restrict__ src = is_q ? (qy + (size_t)(r0 - NB * SKV) * HIN)
                                         : (kv + (size_t)r0 * HIN);
    const float* __restrict__ W  = is_q ? Wq : Wkv;
    const float* __restrict__ bs = is_q ? bq : bkv;

    ((float4*)rowf)[t] = ((const float4*)src)[t];
    __syncthreads();

    float a0 = 0.f, a1 = 0.f;
    const int ra = rh * 2, rb = rh * 2 + 1;
    #pragma unroll 4
    for (int h4 = 0; h4 < 64; ++h4) {
        const float4 r4a = ((const float4*)rowf[ra])[h4];
        const float4 r4b = ((const float4*)rowf[rb])[h4];
        #pragma unroll
        for (int j = 0; j < 4; ++j) {
            const float w = W[(size_t)(h4 * 4 + j) * HA + a];
            a0 = fmaf(((const float*)&r4a)[j], w, a0);
            a1 = fmaf(((const float*)&r4b)[j], w, a1);
        }
    }
    const float bb = bs[a];
    const float e0 = __builtin_amdgcn_exp2f((a0 + bb) * KSC);
    const float e1 = __builtin_amdgcn_exp2f((a1 + bb) * KSC);
    if (is_q) {
        const int r = r0 - NB * SKV;
        eq[(size_t)(r + ra) * HA + a] = e0;
        eq[(size_t)(r + rb) * HA + a] = e1;
    } else {
        const int bI = r0 >> 10, s0 = r0 & 1023;
        float* __restrict__ p =
            ekT + ((size_t)(bI * 32 + (a >> 2)) * SKV + s0) * 4 + (a & 3);
        p[(size_t)ra * 4] = e0;
        p[(size_t)rb * 4] = e1;
    }
}

// ---------------- Kernel B: fused attn, ZERO-LDS hot loops ----------------
// one block = 4 (b,q) rows; 1024 threads (16 waves); grid 256 (1 block/CU).
// Q/wv live in 10 wave-registers (reg k = value k*64+lane); per-iter
// wave-uniform scalars come via v_readlane (uniform dynamic index) — no
// ds_read in phase 2.  Phase 4 reads weights from the wave's OWN lanes
// (s=tid ownership is lane-aligned with the phase-4 slab) via readlane —
// wt_s and one barrier deleted.
__global__ __launch_bounds__(1024) void attn_kernel(
    const float* __restrict__ ekT,         // (b,32,1024,4) interleaved exps
    const float* __restrict__ eq,          // (1024,128) exps, row-major
    const float* __restrict__ wv,          // (128)
    const float* __restrict__ kv,          // (2048,256) f32
    float* __restrict__ out)               // [262144 out0][1048576 weights]
{
    __shared__ __align__(16) float part[16][4][HIN];   // 64 KB
    __shared__ float red[2][4][16];

    const int tid  = threadIdx.x;
    const int lane = tid & 63, wid = tid >> 6;
    const int bq0  = blockIdx.x * 4;       // never straddles b (512%4==0)
    const int b    = bq0 >> 9;

    // ---- wave-register Q/wv: Qr[k] = Q[k>>1][(k&1)*64+lane], wr[h]=wv[h*64+lane]
    float Qr[8], wr[2];
    #pragma unroll
    for (int k = 0; k < 8; ++k)
        Qr[k] = eq[(size_t)(bq0 + (k >> 1)) * HA + (k & 1) * 64 + lane];
    wr[0] = wv[lane];
    wr[1] = wv[64 + lane];

    // ---- phase 2: per-thread s = tid; readlane-sourced uniforms ----
    const float4* __restrict__ E4 =
        (const float4*)ekT + (size_t)b * 32 * SKV + tid;   // + a4*SKV per iter
    float t0 = 0.f, t1 = 0.f, t2 = 0.f, t3 = 0.f;

#define PQH(ACC, QREG)                                                        \
        {                                                                     \
            const float Qx = rlf(QREG, l0);                                   \
            const float Qy = rlf(QREG, l0 + 1);                               \
            const float Qz = rlf(QREG, l0 + 2);                               \
            const float Qw = rlf(QREG, l0 + 3);                               \
            float u  = fmaf(E.x, Qx, 1.f);                                    \
            float v  = fmaf(E.y, Qy, 1.f);                                    \
            ACC = fmaf(fmaf(wx, v, wy * u),                                   \
                       __builtin_amdgcn_rcpf(u * v), ACC);                    \
            float u2 = fmaf(E.z, Qz, 1.f);                                    \
            float v2 = fmaf(E.w, Qw, 1.f);                                    \
            ACC = fmaf(fmaf(wz, v2, ww * u2),                                 \
                       __builtin_amdgcn_rcpf(u2 * v2), ACC);                  \
        }
#define HALF(H)                                                               \
    _Pragma("unroll 4")                                                       \
    for (int a4 = (H) * 16; a4 < (H) * 16 + 16; ++a4) {                       \
        const float4 E = E4[(size_t)a4 * SKV];             /* coalesced */    \
        const int l0 = (4 * a4) & 63;                      /* uniform */      \
        const float wx = rlf(wr[H], l0);                                      \
        const float wy = rlf(wr[H], l0 + 1);                                  \
        const float wz = rlf(wr[H], l0 + 2);                                  \
        const float ww = rlf(wr[H], l0 + 3);                                  \
        PQH(t0, Qr[0 + (H)]) PQH(t1, Qr[2 + (H)])                             \
        PQH(t2, Qr[4 + (H)]) PQH(t3, Qr[6 + (H)])                             \
    }
    HALF(0)
    HALF(1)
#undef HALF
#undef PQH

    // ---- phase 3: softmax over s.  weight ∝ exp(-2*(t - tmin)) ----
    float tq[4] = {t0, t1, t2, t3};
    #pragma unroll
    for (int q = 0; q < 4; ++q) {
        float m = tq[q];
        #pragma unroll
        for (int o = 32; o > 0; o >>= 1) m = fminf(m, __shfl_down(m, o));
        if (lane == 0) red[0][q][wid] = m;
    }
    __syncthreads();
    float M[4];
    #pragma unroll
    for (int q = 0; q < 4; ++q) {
        float m = red[0][q][0];
        #pragma unroll
        for (int i = 1; i < 16; ++i) m = fminf(m, red[0][q][i]);
        M[q] = m;
    }
    float e[4];
    #pragma unroll
    for (int q = 0; q < 4; ++q) {
        e[q] = __builtin_amdgcn_exp2f((M[q] - tq[q]) * KSC);   // exp(-2(t-tmin))
        float sum = e[q];
        #pragma unroll
        for (int o = 32; o > 0; o >>= 1) sum += __shfl_down(sum, o);
        if (lane == 0) red[1][q][wid] = sum;
    }
    __syncthreads();
    float* __restrict__ outw = out + (size_t)NB * NSQ * HIN;   // weights at 262144
    float wgt[4];
    #pragma unroll
    for (int q = 0; q < 4; ++q) {
        float d = red[1][q][0];
        #pragma unroll
        for (int i = 1; i < 16; ++i) d += red[1][q][i];
        wgt[q] = e[q] * __builtin_amdgcn_rcpf(d);
        outw[(size_t)(bq0 + q) * SKV + tid] = wgt[q];          // coalesced per q
    }
    // NO barrier: phase 4 reads weights from this wave's own lanes.

    // ---- phase 4: out[q][h] = sum_s w[q][s]*kv[b][s][h] ----
    // wave g handles s in [g*64, g*64+64); w[q][g*64+i] = lane i's wgt[q].
    {
        const int g = wid;                 // 0..15
        float4 ac0 = {0,0,0,0}, ac1 = {0,0,0,0}, ac2 = {0,0,0,0}, ac3 = {0,0,0,0};
        const float4* __restrict__ kvb =
            (const float4*)kv + (size_t)(b * SKV + g * 64) * 64;
        #pragma unroll 4
        for (int i = 0; i < 64; ++i) {
            const float w0 = rlf(wgt[0], i);             // SGPR broadcast
            const float w1 = rlf(wgt[1], i);
            const float w2 = rlf(wgt[2], i);
            const float w3 = rlf(wgt[3], i);
            const float4 v = kvb[(size_t)i * 64 + lane]; // coalesced 1KB/wave
            ac0.x = fmaf(w0, v.x, ac0.x); ac0.y = fmaf(w0, v.y, ac0.y);
            ac0.z = fmaf(w0, v.z, ac0.z); ac0.w = fmaf(w0, v.w, ac0.w);
            ac1.x = fmaf(w1, v.x, ac1.x); ac1.y = fmaf(w1, v.y, ac1.y);
            ac1.z = fmaf(w1, v.z, ac1.z); ac1.w = fmaf(w1, v.w, ac1.w);
            ac2.x = fmaf(w2, v.x, ac2.x); ac2.y = fmaf(w2, v.y, ac2.y);
            ac2.z = fmaf(w2, v.z, ac2.z); ac2.w = fmaf(w2, v.w, ac2.w);
            ac3.x = fmaf(w3, v.x, ac3.x); ac3.y = fmaf(w3, v.y, ac3.y);
            ac3.z = fmaf(w3, v.z, ac3.z); ac3.w = fmaf(w3, v.w, ac3.w);
        }
        ((float4*)part[g][0])[lane] = ac0;
        ((float4*)part[g][1])[lane] = ac1;
        ((float4*)part[g][2])[lane] = ac2;
        ((float4*)part[g][3])[lane] = ac3;
    }
    __syncthreads();
    {
        const int q = tid >> 8, h = tid & 255;       // 1024 outputs, 1/thread
        float v = 0.f;
        #pragma unroll
        for (int g2 = 0; g2 < 16; ++g2) v += part[g2][q][h];   // stride-1 banks
        out[(size_t)(bq0 + q) * HIN + h] = v;        // coalesced
    }
}

extern "C" void kernel_launch(void* const* d_in, const int* in_sizes, int n_in,
                              void* d_out, int out_size, void* d_ws, size_t ws_size,
                              hipStream_t stream) {
    (void)in_sizes; (void)n_in; (void)out_size; (void)ws_size;
    const float* kv  = (const float*)d_in[0];
    const float* qy  = (const float*)d_in[1];
    const float* Wkv = (const float*)d_in[2];
    const float* bkv = (const float*)d_in[3];
    const float* Wq  = (const float*)d_in[4];
    const float* bq  = (const float*)d_in[5];
    const float* wv  = (const float*)d_in[6];
    float* ekT = (float*)d_ws;                 // 1 MB
    float* eqp = ekT + (size_t)NB * SKV * HA;  // 0.5 MB
    float* out = (float*)d_out;

    hipLaunchKernelGGL(proj_kernel, dim3((NB * SKV + NB * NSQ) / 8), dim3(512), 0, stream,
                       kv, qy, Wkv, bkv, Wq, bq, ekT, eqp);
    hipLaunchKernelGGL(attn_kernel, dim3(NB * NSQ / 4), dim3(1024), 0, stream,
                       ekT, eqp, wv, kv, out);
}